// Round 10
// baseline (574.245 us; speedup 1.0000x reference)
//
#include <hip/hip_runtime.h>

// 16-qubit, depth-4, batch-512 statevector simulator — 5-sweep, packed-FP32.
// R9's balanced 6-sweep (558 us) + the R6 5-sweep fold retried with its two
// failure causes fixed: (1) B_final epilogue = LDS transpose-reduce (not 96
// chained shfls); (2) A_lite(2)'s stolen-gate phase reuses the dead half of
// A[] (no extra Bv registers -> no pressure/spill).
//
// State: 512 x 65536 complex64 = 256 MiB in d_ws.
// Reference qubit q <-> flat-index bit beta = 15-q.
// Memory layout per batch: amp with basis index g stored at m = (g>>3) | ((g&7)<<13).
//
// Partition A (blocks fix g bits 0..2): local j = m bits 0..12, j_b = g_{b+3}.
// Partition B (blocks fix g bits 12..14): local d: d0..8 = g3..11, d9 = g15,
//   d10..12 = g0..2.
//
// Chain perm (16 CNOTs) = main (A-local rows 3..14) o tail (B-local rename
// permB).  Commutations used: L3 gates on q3,q2,q1 (g12..14) commute with
// tail2 (bits 15,0..3) and with L3's B-local gates -> stolen into A_lite(2)
// post-main2 on dest bits D9..11 (= k bits, register-local).  [R6-verified]
// Schedule (5 sweeps):
//   1. qc_B1_gen:   analytic gen (L0+chain0 folded, product tree) + L1 x7.
//   2. qc_A_lite(1,-1): L1 x9 + main1.
//   3. qc_B_heavy(2):   tail1 + L2 x7.
//   4. qc_A_lite(2, 3): L2 x9 + main2 + stolen L3 {q3,q2,q1}.
//   5. qc_B_final:      tail2 + L3 x13 + chain3-relabel expZ (read-only).

#define NQ 16
#define TPB 256

typedef float __attribute__((ext_vector_type(2))) f2;   // (re, im)

__device__ __forceinline__ f2 f2s(float s) { return (f2){s, s}; }

// a (*) b  (complex mul, packed: pk_mul + pk_fma)
__device__ __forceinline__ f2 cmulpk(f2 a, f2 b) {
    f2 bs = { -b.y, b.x };
    f2 r = f2s(a.x) * b;
    return __builtin_elementwise_fma(f2s(a.y), bs, r);
}

// U = RY(t2) * RX(t1) * RZ(t0), row-major [u00,u01,u10,u11]
__device__ __forceinline__ void computeU(const float* params, int layer, int q, f2* U) {
    const float* p = params + (layer*NQ + q)*3;
    float s0, c0, s1, c1, s2, c2;
    sincosf(0.5f*p[0], &s0, &c0);
    sincosf(0.5f*p[1], &s1, &c1);
    sincosf(0.5f*p[2], &s2, &c2);
    f2 m00 = { c1*c0, -c1*s0};
    f2 m01 = { s1*s0, -s1*c0};
    f2 m10 = {-s1*s0, -s1*c0};
    f2 m11 = { c1*c0,  c1*s0};
    U[0] = c2*m00 - s2*m10;
    U[1] = c2*m01 - s2*m11;
    U[2] = s2*m00 + c2*m10;
    U[3] = s2*m01 + c2*m11;
}

// 1q gate on register array A[N], pairing a <-> a|MASK.  8 packed ops/pair.
template<int MASK, int N>
__device__ __forceinline__ void gateN(f2* A, f2 u00, f2 u01, f2 u10, f2 u11) {
    #pragma unroll
    for (int a = 0; a < N; ++a) {
        if (!(a & MASK)) {
            f2 x = A[a], y = A[a | MASK];
            f2 xs = { -x.y, x.x };
            f2 ys = { -y.y, y.x };
            f2 nx = f2s(u00.x) * x;
            nx = __builtin_elementwise_fma(f2s(u00.y), xs, nx);
            nx = __builtin_elementwise_fma(f2s(u01.x), y,  nx);
            nx = __builtin_elementwise_fma(f2s(u01.y), ys, nx);
            f2 ny = f2s(u10.x) * x;
            ny = __builtin_elementwise_fma(f2s(u10.y), xs, ny);
            ny = __builtin_elementwise_fma(f2s(u11.x), y,  ny);
            ny = __builtin_elementwise_fma(f2s(u11.y), ys, ny);
            A[a] = nx; A[a | MASK] = ny;
        }
    }
}
template<int MASK> __device__ __forceinline__ void gate32(f2* A, f2 a, f2 b, f2 c, f2 d) { gateN<MASK,32>(A,a,b,c,d); }
template<int MASK> __device__ __forceinline__ void gate16(f2* A, f2 a, f2 b, f2 c, f2 d) { gateN<MASK,16>(A,a,b,c,d); }

// tail perm on B's register coords (bits = d0, d9, d10, d11, d12)
__device__ __forceinline__ constexpr int permB(int ad) {
    return (ad & 1)
         | ((((ad >> 1) ^ (ad >> 2)) & 1) << 1)
         | ((((ad >> 2) ^ (ad >> 3)) & 1) << 2)
         | ((((ad >> 3) ^ (ad >> 4)) & 1) << 3)
         | ((((ad >> 4) ^  ad      ) & 1) << 4);
}

// Transpose arr1 {0,9,10,11,12} -> arr3 {5,6,7,8,12}
__device__ __forceinline__ void transpose_1to3(f2* A, f2* S, int t) {
    #pragma unroll
    for (int h = 0; h < 2; ++h) {
        __syncthreads();
        #pragma unroll
        for (int c = 0; c < 8; ++c) {
            int slot = ((t << 1) | (c << 9)) ^ (((t >> 4) & 7) << 1);
            f2 a0 = A[h*16 + 2*c], a1 = A[h*16 + 2*c + 1];
            *(float4*)&S[slot] = make_float4(a0.x, a0.y, a1.x, a1.y);
        }
        __syncthreads();
        #pragma unroll
        for (int rr = 0; rr < 16; ++rr) {
            int jj = (t & 31) | (rr << 5) | (((t >> 5) & 7) << 9);
            A[h*16 + rr] = S[jj ^ ((rr & 7) << 1)];
        }
    }
}

// Transpose arr1 {0,9,10,11,12} -> arr2 {1,2,3,4,12}
__device__ __forceinline__ void transpose_1to2(f2* A, f2* S, int t) {
    #pragma unroll
    for (int h = 0; h < 2; ++h) {
        __syncthreads();
        #pragma unroll
        for (int c = 0; c < 8; ++c) {
            int slot = ((t << 1) | (c << 9)) ^ (((t >> 4) & 7) << 1);
            f2 a0 = A[h*16 + 2*c], a1 = A[h*16 + 2*c + 1];
            *(float4*)&S[slot] = make_float4(a0.x, a0.y, a1.x, a1.y);
        }
        __syncthreads();
        #pragma unroll
        for (int rr = 0; rr < 16; ++rr) {
            int jj = (t & 1) | (rr << 1) | (((t >> 1) & 15) << 5) | (((t >> 5) & 7) << 9);
            A[h*16 + rr] = S[jj ^ (((t >> 1) & 7) << 1)];
        }
    }
}

// Transpose arr2 {1,2,3,4,12} -> arr3 {5,6,7,8,12}
__device__ __forceinline__ void transpose_2to3(f2* A, f2* S, int t) {
    #pragma unroll
    for (int h = 0; h < 2; ++h) {
        __syncthreads();
        #pragma unroll
        for (int rr = 0; rr < 16; ++rr) {
            int jj = (t & 1) | (rr << 1) | (((t >> 1) & 15) << 5) | (((t >> 5) & 7) << 9);
            S[jj ^ (((t >> 1) & 7) << 1)] = A[h*16 + rr];
        }
        __syncthreads();
        #pragma unroll
        for (int rr = 0; rr < 16; ++rr) {
            int jj = (t & 31) | (rr << 5) | (((t >> 5) & 7) << 9);
            A[h*16 + rr] = S[jj ^ ((rr & 7) << 1)];
        }
    }
}

// B-mid Ush (7): 0:q15(d10) 1:q14(d11) 2:q13(d12) 3:q7(d5) 4:q6(d6) 5:q5(d7) 6:q4(d8)
__device__ __forceinline__ int b_qb(int tt) { return (tt < 3) ? (15 - tt) : (10 - tt); }
// A-sweep Ush (9): 0:q12(j0) 1:q3(j9) 2:q2(j10) 3:q1(j11) 4:q0(j12)
//                  5:q11(j1) 6:q10(j2) 7:q9(j3) 8:q8(j4)
__device__ __forceinline__ int a_qb(int tt) { return (tt == 0) ? 12 : (tt < 5) ? (4 - tt) : (16 - tt); }
// B_final Ush (13): 0:q12(d0) 1:q0(d9) 2:q15(d10) 3:q14(d11) 4:q13(d12)
//                   5..8: q11..q8 (d1..4)   9..12: q7..q4 (d5..8)
__device__ __forceinline__ int bf_qb(int tt) {
    return (tt == 0) ? 12 : (tt == 1) ? 0 : (tt < 5) ? (17 - tt) : (16 - tt);
}

// Sweep 1: fused analytic generation + L1 x7.  No amplitude loads.
__global__ __launch_bounds__(TPB, 4) void qc_B1_gen(
    const float* __restrict__ x, const float* __restrict__ params,
    f2* __restrict__ st)
{
    __shared__ __align__(16) f2 S[4096];       // 32 KB transpose buffer
    __shared__ f2 Ush[7][4];
    __shared__ f2 V[16][2];

    const int t    = threadIdx.x;
    const int b    = blockIdx.x >> 3;
    const int fixb = blockIdx.x & 7;            // g bits 12..14
    f2* base = st + ((size_t)b << NQ);

    if (t < 16) {                               // qubit t, g bit 15-t
        f2 U[4];
        computeU(params, 0, t, U);
        float s, c;
        sincosf(0.5f * x[b*NQ + t], &s, &c);
        // w = U * (cos h, -i sin h)^T
        V[15 - t][0] = (f2){U[0].x*c + U[1].y*s, U[0].y*c - U[1].x*s};
        V[15 - t][1] = (f2){U[2].x*c + U[3].y*s, U[2].y*c - U[3].x*s};
    } else if (t < 23) {                        // layer-1 gate table (7)
        int tt = t - 16;
        computeU(params, 1, b_qb(tt), Ush[tt]);
    }
    __syncthreads();                             // V + Ush ready

    const int f0 = fixb & 1, f1 = (fixb >> 1) & 1, f2b = (fixb >> 2) & 1;
    const int t0 = t & 1,  t7 = (t >> 7) & 1;

    // pre = prod_{beta=4..13}
    f2 pre = V[4][(t ^ (t >> 1)) & 1];
    #pragma unroll
    for (int bb = 5; bb <= 10; ++bb)
        pre = cmulpk(pre, V[bb][((t >> (bb - 4)) ^ (t >> (bb - 3))) & 1]);
    pre = cmulpk(pre, V[11][t7 ^ f0]);
    pre = cmulpk(pre, V[12][f0 ^ f1]);
    pre = cmulpk(pre, V[13][f1 ^ f2b]);

    f2 P0 = cmulpk(pre, V[3][t0]);               // a0=0
    f2 P1 = cmulpk(pre, V[3][1 ^ t0]);           // a0=1
    f2 Q[4];                                     // Q[a0 + 2*e4] = P[a0]*V[2][e4]
    Q[0] = cmulpk(P0, V[2][0]); Q[1] = cmulpk(P1, V[2][0]);
    Q[2] = cmulpk(P0, V[2][1]); Q[3] = cmulpk(P1, V[2][1]);
    f2 Rr[4];                                    // Rr[e2 + 2*e3] = V[0][e2]*V[1][e3]
    Rr[0] = cmulpk(V[0][0], V[1][0]); Rr[1] = cmulpk(V[0][1], V[1][0]);
    Rr[2] = cmulpk(V[0][0], V[1][1]); Rr[3] = cmulpk(V[0][1], V[1][1]);
    f2 G0 = cmulpk(V[15][0], V[14][f2b]);        // e1=0
    f2 G1 = cmulpk(V[15][1], V[14][1 ^ f2b]);    // e1=1
    f2 TT[8];                                    // TT[e1 + 2*e2 + 4*e3]
    #pragma unroll
    for (int e = 0; e < 4; ++e) {
        TT[2*e]     = cmulpk(G0, Rr[e]);
        TT[2*e + 1] = cmulpk(G1, Rr[e]);
    }

    f2 A[32];
    #pragma unroll
    for (int a = 0; a < 32; ++a) {
        const int a0 = a & 1;
        const int e1 = ((a >> 1) ^ (a >> 2)) & 1;
        const int e2 = ((a >> 2) ^ (a >> 3)) & 1;
        const int e3 = ((a >> 3) ^ (a >> 4)) & 1;
        const int e4 = ((a >> 4) ^  a      ) & 1;
        A[a] = cmulpk(Q[a0 + 2*e4], TT[e1 + 2*e2 + 4*e3]);
    }

    // arr1 gates (layer 1): d10..12 -> q15,q14,q13
    gate32<4> (A, Ush[0][0], Ush[0][1], Ush[0][2], Ush[0][3]);
    gate32<8> (A, Ush[1][0], Ush[1][1], Ush[1][2], Ush[1][3]);
    gate32<16>(A, Ush[2][0], Ush[2][1], Ush[2][2], Ush[2][3]);

    transpose_1to3(A, S, t);
    gate32<1>(A, Ush[3][0], Ush[3][1], Ush[3][2], Ush[3][3]);   // d5 q7
    gate32<2>(A, Ush[4][0], Ush[4][1], Ush[4][2], Ush[4][3]);   // d6 q6
    gate32<4>(A, Ush[5][0], Ush[5][1], Ush[5][2], Ush[5][3]);   // d7 q5
    gate32<8>(A, Ush[6][0], Ush[6][1], Ush[6][2], Ush[6][3]);   // d8 q4

    // direct store from arr3 (no perm)
    #pragma unroll
    for (int h = 0; h < 2; ++h) {
        #pragma unroll
        for (int rr = 0; rr < 16; ++rr) {
            int d = (t & 31) | (rr << 5) | (((t >> 5) & 7) << 9) | (h << 12);
            int m = (d & 511) | (fixb << 9) | (((d >> 9) & 1) << 12) | ((d >> 10) << 13);
            base[m] = A[h*16 + rr];
        }
    }
}

// Sweep 3: tail(lm-1) rename + layer-lm gates on 7 B-local qubits.
__global__ __launch_bounds__(TPB, 4) void qc_B_heavy(
    const float* __restrict__ params, f2* __restrict__ st, int lm)
{
    __shared__ __align__(16) f2 S[4096];
    __shared__ f2 Ush[7][4];

    const int t    = threadIdx.x;
    const int b    = blockIdx.x >> 3;
    const int fixb = blockIdx.x & 7;            // g bits 12..14
    f2* base = st + ((size_t)b << NQ);

    if (t < 7) computeU(params, lm, b_qb(t), Ush[t]);

    // load arr1-d: reg a: bit0 = d0, bits1..4 = d9..12; thread bits = d1..8
    f2 R[32];
    #pragma unroll
    for (int k = 0; k < 16; ++k) {
        int j = 2*(t + 256*k);
        int m = (j & 511) | (fixb << 9) | (((j >> 9) & 1) << 12) | ((j >> 10) << 13);
        float4 v = *(const float4*)(base + m);
        R[2*k]   = (f2){v.x, v.y};
        R[2*k+1] = (f2){v.z, v.w};
    }
    // tail perm of layer lm-1: pure compile-time register rename
    f2 A[32];
    #pragma unroll
    for (int a = 0; a < 32; ++a) A[a] = R[permB(a)];
    __syncthreads();                             // Ush ready

    // arr1 gates (layer lm): d10..12 -> q15,q14,q13
    gate32<4> (A, Ush[0][0], Ush[0][1], Ush[0][2], Ush[0][3]);
    gate32<8> (A, Ush[1][0], Ush[1][1], Ush[1][2], Ush[1][3]);
    gate32<16>(A, Ush[2][0], Ush[2][1], Ush[2][2], Ush[2][3]);

    transpose_1to3(A, S, t);
    gate32<1>(A, Ush[3][0], Ush[3][1], Ush[3][2], Ush[3][3]);   // d5 q7
    gate32<2>(A, Ush[4][0], Ush[4][1], Ush[4][2], Ush[4][3]);   // d6 q6
    gate32<4>(A, Ush[5][0], Ush[5][1], Ush[5][2], Ush[5][3]);   // d7 q5
    gate32<8>(A, Ush[6][0], Ush[6][1], Ush[6][2], Ush[6][3]);   // d8 q4

    // direct store from arr3 (no perm)
    #pragma unroll
    for (int h = 0; h < 2; ++h) {
        #pragma unroll
        for (int rr = 0; rr < 16; ++rr) {
            int d = (t & 31) | (rr << 5) | (((t >> 5) & 7) << 9) | (h << 12);
            int m = (d & 511) | (fixb << 9) | (((d >> 9) & 1) << 12) | ((d >> 10) << 13);
            base[m] = A[h*16 + rr];
        }
    }
}

// Sweeps 2,4: layer-l gates x9 (5 natural + 4 after nat->arr2 transpose)
// + main(l) + (stealL>=0: stolen layer-stealL gates q3,q2,q1 on dest bits
// D9..11 = k bits, applied in-place on the dead half of A[]).
__global__ __launch_bounds__(TPB, 4) void qc_A_lite(
    const float* __restrict__ params, f2* __restrict__ st, int layer, int stealL)
{
    __shared__ __align__(16) f2 S[4096];
    __shared__ f2 Ush[9][4];
    __shared__ f2 Uq[3][4];
    const int t    = threadIdx.x;
    const int b    = blockIdx.x >> 3;
    const int fix3 = blockIdx.x & 7;
    f2* base = st + ((size_t)b << NQ) + (fix3 << 13);

    if (t < 9) computeU(params, layer, a_qb(t), Ush[t]);
    if (stealL >= 0 && t >= 16 && t < 19)        // Uq[0]=q3 Uq[1]=q2 Uq[2]=q1
        computeU(params, stealL, 3 - (t - 16), Uq[t - 16]);

    f2 A[32];
    const float4* src = (const float4*)base;
    #pragma unroll
    for (int k = 0; k < 16; ++k) {
        float4 v = src[t + 256*k];
        A[2*k]   = (f2){v.x, v.y};
        A[2*k+1] = (f2){v.z, v.w};
    }
    __syncthreads();                             // U tables ready

    // natural gates: j0 q12, j9 q3, j10 q2, j11 q1, j12 q0
    gate32<1> (A, Ush[0][0], Ush[0][1], Ush[0][2], Ush[0][3]);
    gate32<2> (A, Ush[1][0], Ush[1][1], Ush[1][2], Ush[1][3]);
    gate32<4> (A, Ush[2][0], Ush[2][1], Ush[2][2], Ush[2][3]);
    gate32<8> (A, Ush[3][0], Ush[3][1], Ush[3][2], Ush[3][3]);
    gate32<16>(A, Ush[4][0], Ush[4][1], Ush[4][2], Ush[4][3]);

    transpose_1to2(A, S, t);
    // arr2 gates: j1 q11, j2 q10, j3 q9, j4 q8
    gate32<1>(A, Ush[5][0], Ush[5][1], Ush[5][2], Ush[5][3]);
    gate32<2>(A, Ush[6][0], Ush[6][1], Ush[6][2], Ush[6][3]);
    gate32<4>(A, Ush[7][0], Ush[7][1], Ush[7][2], Ush[7][3]);
    gate32<8>(A, Ush[8][0], Ush[8][1], Ush[8][2], Ush[8][3]);

    // writeback: stage at arr2 positions, perm-read back into the (now dead)
    // half of A, optional stolen gates, store coalesced.
    float4* dst = (float4*)base;
    #pragma unroll
    for (int h = 0; h < 2; ++h) {
        __syncthreads();
        #pragma unroll
        for (int rr = 0; rr < 16; ++rr) {        // arr2 positions
            int jj = (t & 1) | (rr << 1) | (((t >> 1) & 15) << 5) | (((t >> 5) & 7) << 9);
            S[jj ^ (((t >> 1) & 7) << 1)] = A[h*16 + rr];
        }
        __syncthreads();
        #pragma unroll
        for (int k = 0; k < 8; ++k) {            // dest d' = 2(t+256k), bit12 = h
            int d  = 2*(t + 256*k);
            int i0 = d ^ (d >> 1) ^ (h << 11);
            int i1 = (d+1) ^ ((d+1) >> 1) ^ (h << 11);
            A[h*16 + 2*k]     = S[i0 ^ (((i0 >> 5) & 7) << 1)];
            A[h*16 + 2*k + 1] = S[i1 ^ (((i1 >> 5) & 7) << 1)];
        }
        if (stealL >= 0) {                       // dest-reg bits: 0=D0, 1..3=D9..11
            gate16<2>(&A[h*16], Uq[0][0], Uq[0][1], Uq[0][2], Uq[0][3]);  // D9  q3
            gate16<4>(&A[h*16], Uq[1][0], Uq[1][1], Uq[1][2], Uq[1][3]);  // D10 q2
            gate16<8>(&A[h*16], Uq[2][0], Uq[2][1], Uq[2][2], Uq[2][3]);  // D11 q1
        }
        #pragma unroll
        for (int k = 0; k < 8; ++k) {
            f2 a0 = A[h*16 + 2*k], a1 = A[h*16 + 2*k + 1];
            dst[(t + 256*k) | (h << 11)] = make_float4(a0.x, a0.y, a1.x, a1.y);
        }
    }
}

// Sweep 5: tail2 rename + L3 x13 + chain3-relabel expZ.  Read-only.
// arr3 amp coords: g0=t6, g1=t7, g2=h, g3..7=t0..4, g8..11=rr, g12..14=fixb,
// g15=t5.  Final f_b = parity(g>>b) (b<=14), f15 = parity(g&0x7FFF).
// Sign buckets over (rr,h): M0 uniform; M1 ±par(rr); M2 ±par(rr>>1);
// M3 ±par(rr>>2); M4 ±rr3; M5 ±(par(rr)^h).  [R6-verified algebra]
__global__ __launch_bounds__(TPB, 4) void qc_B_final(
    const float* __restrict__ params, const f2* __restrict__ st,
    float* __restrict__ out)
{
    __shared__ __align__(16) f2 S[4096];         // transpose buffer, reused as F
    __shared__ f2 Ush[13][4];
    float* F = (float*)S;                         // 16*272 = 4352 floats <= 8192

    const int t    = threadIdx.x;
    const int b    = blockIdx.x >> 3;
    const int fixb = blockIdx.x & 7;
    const f2* base = st + ((size_t)b << NQ);

    if (t < 13) computeU(params, 3, bf_qb(t), Ush[t]);

    f2 R[32];
    #pragma unroll
    for (int k = 0; k < 16; ++k) {
        int j = 2*(t + 256*k);
        int m = (j & 511) | (fixb << 9) | (((j >> 9) & 1) << 12) | ((j >> 10) << 13);
        float4 v = *(const float4*)(base + m);
        R[2*k]   = (f2){v.x, v.y};
        R[2*k+1] = (f2){v.z, v.w};
    }
    f2 A[32];
    #pragma unroll
    for (int a = 0; a < 32; ++a) A[a] = R[permB(a)];   // tail2 rename
    __syncthreads();                             // Ush ready

    // arr1 gates: d0 q12, d9 q0, d10..12 q15,q14,q13
    gate32<1> (A, Ush[0][0],  Ush[0][1],  Ush[0][2],  Ush[0][3]);
    gate32<2> (A, Ush[1][0],  Ush[1][1],  Ush[1][2],  Ush[1][3]);
    gate32<4> (A, Ush[2][0],  Ush[2][1],  Ush[2][2],  Ush[2][3]);
    gate32<8> (A, Ush[3][0],  Ush[3][1],  Ush[3][2],  Ush[3][3]);
    gate32<16>(A, Ush[4][0],  Ush[4][1],  Ush[4][2],  Ush[4][3]);

    transpose_1to2(A, S, t);
    // arr2 gates: d1..4 -> q11,q10,q9,q8
    gate32<1>(A, Ush[5][0], Ush[5][1], Ush[5][2], Ush[5][3]);
    gate32<2>(A, Ush[6][0], Ush[6][1], Ush[6][2], Ush[6][3]);
    gate32<4>(A, Ush[7][0], Ush[7][1], Ush[7][2], Ush[7][3]);
    gate32<8>(A, Ush[8][0], Ush[8][1], Ush[8][2], Ush[8][3]);

    transpose_2to3(A, S, t);
    // arr3 gates: d5..8 -> q7,q6,q5,q4
    gate32<1>(A, Ush[9][0],  Ush[9][1],  Ush[9][2],  Ush[9][3]);
    gate32<2>(A, Ush[10][0], Ush[10][1], Ush[10][2], Ush[10][3]);
    gate32<4>(A, Ush[11][0], Ush[11][1], Ush[11][2], Ush[11][3]);
    gate32<8>(A, Ush[12][0], Ush[12][1], Ush[12][2], Ush[12][3]);

    // 6 sign buckets over register slots (h, rr)
    float M0 = 0.f, M1 = 0.f, M2 = 0.f, M3 = 0.f, M4 = 0.f, M5 = 0.f;
    #pragma unroll
    for (int h = 0; h < 2; ++h) {
        #pragma unroll
        for (int rr = 0; rr < 16; ++rr) {
            f2 v = A[h*16 + rr];
            float p = v.x*v.x + v.y*v.y;
            M0 += p;
            M1 += (__popc(rr)      & 1) ? -p : p;
            M2 += (__popc(rr >> 1) & 1) ? -p : p;
            M3 += (__popc(rr >> 2) & 1) ? -p : p;
            M4 += (rr >> 3)             ? -p : p;
            M5 += ((__popc(rr) ^ h) & 1) ? -p : p;
        }
    }

    const int pf   = __popc(fixb) & 1;
    const int t5b  = (t >> 5) & 1, t6b = (t >> 6) & 1, t7b = (t >> 7) & 1;
    const int pt04 = __popc(t & 31) & 1;
    const int bs   = pf ^ t5b;                   // base sign for mid qubits

    float acc[NQ];
    acc[0]  = ((t6b ^ t7b ^ pt04 ^ pf) & 1) ? -M5 : M5;          // q0  (f15)
    acc[1]  = (((fixb >> 2) ^ t5b) & 1)      ? -M0 : M0;          // q1  (f14)
    acc[2]  = ((__popc(fixb >> 1) ^ t5b) & 1)? -M0 : M0;          // q2  (f13)
    acc[3]  = (bs & 1)                        ? -M0 : M0;          // q3  (f12)
    acc[4]  = (bs & 1)                        ? -M4 : M4;          // q4  (f11)
    acc[5]  = (bs & 1)                        ? -M3 : M3;          // q5  (f10)
    acc[6]  = (bs & 1)                        ? -M2 : M2;          // q6  (f9)
    acc[7]  = (bs & 1)                        ? -M1 : M1;          // q7  (f8)
    acc[8]  = ((((t >> 4) & 1) ^ bs) & 1)     ? -M1 : M1;          // q8  (f7)
    acc[9]  = ((__popc((t >> 3) & 3)  ^ bs) & 1) ? -M1 : M1;       // q9  (f6)
    acc[10] = ((__popc((t >> 2) & 7)  ^ bs) & 1) ? -M1 : M1;       // q10 (f5)
    acc[11] = ((__popc((t >> 1) & 15) ^ bs) & 1) ? -M1 : M1;       // q11 (f4)
    acc[12] = ((pt04 ^ bs) & 1)               ? -M1 : M1;          // q12 (f3)
    acc[13] = ((pt04 ^ bs) & 1)               ? -M5 : M5;          // q13 (f2)
    acc[14] = ((t7b ^ pt04 ^ bs) & 1)         ? -M5 : M5;          // q14 (f1)
    acc[15] = ((t6b ^ t7b ^ pt04 ^ bs) & 1)   ? -M5 : M5;          // q15 (f0)

    __syncthreads();                             // S reads done; reuse as F
    #pragma unroll
    for (int q = 0; q < NQ; ++q) F[q*272 + t] = acc[q];
    __syncthreads();
    const int qq = t >> 4, ii = t & 15;
    float s = 0.f;
    #pragma unroll
    for (int c = 0; c < 16; ++c) s += F[qq*272 + ii + 16*c];
    s += __shfl_down(s, 8, 16);
    s += __shfl_down(s, 4, 16);
    s += __shfl_down(s, 2, 16);
    s += __shfl_down(s, 1, 16);
    if (ii == 0) atomicAdd(&out[b*NQ + qq], s);
}

extern "C" void kernel_launch(void* const* d_in, const int* in_sizes, int n_in,
                              void* d_out, int out_size, void* d_ws, size_t ws_size,
                              hipStream_t stream)
{
    (void)in_sizes; (void)n_in; (void)ws_size;
    const float* x      = (const float*)d_in[0];   // (512,16) fp32
    const float* params = (const float*)d_in[1];   // (4,16,3) fp32
    float* out = (float*)d_out;                    // (512,16) fp32
    f2* st = (f2*)d_ws;                            // 256 MiB state

    hipMemsetAsync(d_out, 0, (size_t)out_size * sizeof(float), stream);
    qc_B1_gen <<<dim3(512*8), dim3(TPB), 0, stream>>>(x, params, st);
    qc_A_lite <<<dim3(512*8), dim3(TPB), 0, stream>>>(params, st, 1, -1);
    qc_B_heavy<<<dim3(512*8), dim3(TPB), 0, stream>>>(params, st, 2);
    qc_A_lite <<<dim3(512*8), dim3(TPB), 0, stream>>>(params, st, 2, 3);
    qc_B_final<<<dim3(512*8), dim3(TPB), 0, stream>>>(params, st, out);
}

// Round 11
// 541.172 us; speedup vs baseline: 1.0611x; 1.0611x over previous
//
#include <hip/hip_runtime.h>

// 16-qubit, depth-4, batch-512 statevector simulator — 5-sweep, packed-FP32.
// R10 fold retried with the A_lite writeback REVERTED to R9's interleaved
// {LDS-read -> immediate float4 store} form (R10's read-into-A-then-burst-store
// caused sector write amplification: WRITE 256->372 MB, 96->148 us).  The
// stolen L3 {q3,q2,q1} gates are applied IN THE STAGED LDS ARRAY instead:
// dest-bit pairings map through i = d^(d>>1) to XOR masks 3/6/12 on i-bits
// 8..11 with roles d9=i9^i10^i11^h, d10=i10^i11^h, d11=i11^h.
//
// State: 512 x 65536 complex64 = 256 MiB in d_ws.
// Reference qubit q <-> flat-index bit beta = 15-q.
// Memory layout per batch: amp with basis index g stored at m = (g>>3) | ((g&7)<<13).
//
// Partition A (blocks fix g bits 0..2): local j = m bits 0..12, j_b = g_{b+3}.
// Partition B (blocks fix g bits 12..14): local d: d0..8 = g3..11, d9 = g15,
//   d10..12 = g0..2.
//
// Chain perm (16 CNOTs) = main (A-local rows 3..14) o tail (B-local rename
// permB).  L3 gates on q3,q2,q1 (g12..14) commute with tail2 and with L3's
// B-local gates -> applied post-main2 inside A_lite(2).  [R10-verified math]
// Schedule (5 sweeps):
//   1. qc_B1_gen:   analytic gen (L0+chain0 folded, product tree) + L1 x7.
//   2. qc_A_lite(1,-1): L1 x9 + main1.
//   3. qc_B_heavy(2):   tail1 + L2 x7.
//   4. qc_A_lite(2, 3): L2 x9 + main2 + stolen L3 {q3,q2,q1} (LDS pass).
//   5. qc_B_final:      tail2 + L3 x13 + chain3-relabel expZ (read-only).

#define NQ 16
#define TPB 256

typedef float __attribute__((ext_vector_type(2))) f2;   // (re, im)

__device__ __forceinline__ f2 f2s(float s) { return (f2){s, s}; }

// a (*) b  (complex mul, packed: pk_mul + pk_fma)
__device__ __forceinline__ f2 cmulpk(f2 a, f2 b) {
    f2 bs = { -b.y, b.x };
    f2 r = f2s(a.x) * b;
    return __builtin_elementwise_fma(f2s(a.y), bs, r);
}

// U = RY(t2) * RX(t1) * RZ(t0), row-major [u00,u01,u10,u11]
__device__ __forceinline__ void computeU(const float* params, int layer, int q, f2* U) {
    const float* p = params + (layer*NQ + q)*3;
    float s0, c0, s1, c1, s2, c2;
    sincosf(0.5f*p[0], &s0, &c0);
    sincosf(0.5f*p[1], &s1, &c1);
    sincosf(0.5f*p[2], &s2, &c2);
    f2 m00 = { c1*c0, -c1*s0};
    f2 m01 = { s1*s0, -s1*c0};
    f2 m10 = {-s1*s0, -s1*c0};
    f2 m11 = { c1*c0,  c1*s0};
    U[0] = c2*m00 - s2*m10;
    U[1] = c2*m01 - s2*m11;
    U[2] = s2*m00 + c2*m10;
    U[3] = s2*m01 + c2*m11;
}

// 1q gate on register array A[N], pairing a <-> a|MASK.  8 packed ops/pair.
template<int MASK, int N>
__device__ __forceinline__ void gateN(f2* A, f2 u00, f2 u01, f2 u10, f2 u11) {
    #pragma unroll
    for (int a = 0; a < N; ++a) {
        if (!(a & MASK)) {
            f2 x = A[a], y = A[a | MASK];
            f2 xs = { -x.y, x.x };
            f2 ys = { -y.y, y.x };
            f2 nx = f2s(u00.x) * x;
            nx = __builtin_elementwise_fma(f2s(u00.y), xs, nx);
            nx = __builtin_elementwise_fma(f2s(u01.x), y,  nx);
            nx = __builtin_elementwise_fma(f2s(u01.y), ys, nx);
            f2 ny = f2s(u10.x) * x;
            ny = __builtin_elementwise_fma(f2s(u10.y), xs, ny);
            ny = __builtin_elementwise_fma(f2s(u11.x), y,  ny);
            ny = __builtin_elementwise_fma(f2s(u11.y), ys, ny);
            A[a] = nx; A[a | MASK] = ny;
        }
    }
}
template<int MASK> __device__ __forceinline__ void gate32(f2* A, f2 a, f2 b, f2 c, f2 d) { gateN<MASK,32>(A,a,b,c,d); }

// Gate on 16-element label array E with XOR-pair mask M and role
// par(x & RM) ^ h; element with role 0 is the "row 0" operand.
template<int M, int RM>
__device__ __forceinline__ void gateE(f2* E, int h, f2 u00, f2 u01, f2 u10, f2 u11) {
    #pragma unroll
    for (int x = 0; x < 16; ++x) {
        if ((__popc(x & RM) & 1) == h && (x < (x ^ M) || ((__popc((x^M) & RM) & 1) == h))) {
            // exactly one element of each pair has role 0; process at that one
        }
    }
    #pragma unroll
    for (int x = 0; x < 16; ++x) {
        if ((__popc(x & RM) & 1) == 0) {         // role before h-fold handled below
        }
    }
    // (simple explicit form)
    #pragma unroll
    for (int x = 0; x < 16; ++x) {
        int r = (__popc(x & RM) & 1) ^ h;
        if (r == 0) {
            int y = x ^ M;
            f2 xx = E[x], yy = E[y];
            f2 xs = { -xx.y, xx.x };
            f2 ys = { -yy.y, yy.x };
            f2 nx = f2s(u00.x) * xx;
            nx = __builtin_elementwise_fma(f2s(u00.y), xs, nx);
            nx = __builtin_elementwise_fma(f2s(u01.x), yy, nx);
            nx = __builtin_elementwise_fma(f2s(u01.y), ys, nx);
            f2 ny = f2s(u10.x) * xx;
            ny = __builtin_elementwise_fma(f2s(u10.y), xs, ny);
            ny = __builtin_elementwise_fma(f2s(u11.x), yy, ny);
            ny = __builtin_elementwise_fma(f2s(u11.y), ys, ny);
            E[x] = nx; E[y] = ny;
        }
    }
}

// tail perm on B's register coords (bits = d0, d9, d10, d11, d12)
__device__ __forceinline__ constexpr int permB(int ad) {
    return (ad & 1)
         | ((((ad >> 1) ^ (ad >> 2)) & 1) << 1)
         | ((((ad >> 2) ^ (ad >> 3)) & 1) << 2)
         | ((((ad >> 3) ^ (ad >> 4)) & 1) << 3)
         | ((((ad >> 4) ^  ad      ) & 1) << 4);
}

// Transpose arr1 {0,9,10,11,12} -> arr3 {5,6,7,8,12}
__device__ __forceinline__ void transpose_1to3(f2* A, f2* S, int t) {
    #pragma unroll
    for (int h = 0; h < 2; ++h) {
        __syncthreads();
        #pragma unroll
        for (int c = 0; c < 8; ++c) {
            int slot = ((t << 1) | (c << 9)) ^ (((t >> 4) & 7) << 1);
            f2 a0 = A[h*16 + 2*c], a1 = A[h*16 + 2*c + 1];
            *(float4*)&S[slot] = make_float4(a0.x, a0.y, a1.x, a1.y);
        }
        __syncthreads();
        #pragma unroll
        for (int rr = 0; rr < 16; ++rr) {
            int jj = (t & 31) | (rr << 5) | (((t >> 5) & 7) << 9);
            A[h*16 + rr] = S[jj ^ ((rr & 7) << 1)];
        }
    }
}

// Transpose arr1 {0,9,10,11,12} -> arr2 {1,2,3,4,12}
__device__ __forceinline__ void transpose_1to2(f2* A, f2* S, int t) {
    #pragma unroll
    for (int h = 0; h < 2; ++h) {
        __syncthreads();
        #pragma unroll
        for (int c = 0; c < 8; ++c) {
            int slot = ((t << 1) | (c << 9)) ^ (((t >> 4) & 7) << 1);
            f2 a0 = A[h*16 + 2*c], a1 = A[h*16 + 2*c + 1];
            *(float4*)&S[slot] = make_float4(a0.x, a0.y, a1.x, a1.y);
        }
        __syncthreads();
        #pragma unroll
        for (int rr = 0; rr < 16; ++rr) {
            int jj = (t & 1) | (rr << 1) | (((t >> 1) & 15) << 5) | (((t >> 5) & 7) << 9);
            A[h*16 + rr] = S[jj ^ (((t >> 1) & 7) << 1)];
        }
    }
}

// Transpose arr2 {1,2,3,4,12} -> arr3 {5,6,7,8,12}
__device__ __forceinline__ void transpose_2to3(f2* A, f2* S, int t) {
    #pragma unroll
    for (int h = 0; h < 2; ++h) {
        __syncthreads();
        #pragma unroll
        for (int rr = 0; rr < 16; ++rr) {
            int jj = (t & 1) | (rr << 1) | (((t >> 1) & 15) << 5) | (((t >> 5) & 7) << 9);
            S[jj ^ (((t >> 1) & 7) << 1)] = A[h*16 + rr];
        }
        __syncthreads();
        #pragma unroll
        for (int rr = 0; rr < 16; ++rr) {
            int jj = (t & 31) | (rr << 5) | (((t >> 5) & 7) << 9);
            A[h*16 + rr] = S[jj ^ ((rr & 7) << 1)];
        }
    }
}

// B-mid Ush (7): 0:q15(d10) 1:q14(d11) 2:q13(d12) 3:q7(d5) 4:q6(d6) 5:q5(d7) 6:q4(d8)
__device__ __forceinline__ int b_qb(int tt) { return (tt < 3) ? (15 - tt) : (10 - tt); }
// A-sweep Ush (9): 0:q12(j0) 1:q3(j9) 2:q2(j10) 3:q1(j11) 4:q0(j12)
//                  5:q11(j1) 6:q10(j2) 7:q9(j3) 8:q8(j4)
__device__ __forceinline__ int a_qb(int tt) { return (tt == 0) ? 12 : (tt < 5) ? (4 - tt) : (16 - tt); }
// B_final Ush (13): 0:q12(d0) 1:q0(d9) 2:q15(d10) 3:q14(d11) 4:q13(d12)
//                   5..8: q11..q8 (d1..4)   9..12: q7..q4 (d5..8)
__device__ __forceinline__ int bf_qb(int tt) {
    return (tt == 0) ? 12 : (tt == 1) ? 0 : (tt < 5) ? (17 - tt) : (16 - tt);
}

// Sweep 1: fused analytic generation + L1 x7.  No amplitude loads.
__global__ __launch_bounds__(TPB, 4) void qc_B1_gen(
    const float* __restrict__ x, const float* __restrict__ params,
    f2* __restrict__ st)
{
    __shared__ __align__(16) f2 S[4096];       // 32 KB transpose buffer
    __shared__ f2 Ush[7][4];
    __shared__ f2 V[16][2];

    const int t    = threadIdx.x;
    const int b    = blockIdx.x >> 3;
    const int fixb = blockIdx.x & 7;            // g bits 12..14
    f2* base = st + ((size_t)b << NQ);

    if (t < 16) {                               // qubit t, g bit 15-t
        f2 U[4];
        computeU(params, 0, t, U);
        float s, c;
        sincosf(0.5f * x[b*NQ + t], &s, &c);
        // w = U * (cos h, -i sin h)^T
        V[15 - t][0] = (f2){U[0].x*c + U[1].y*s, U[0].y*c - U[1].x*s};
        V[15 - t][1] = (f2){U[2].x*c + U[3].y*s, U[2].y*c - U[3].x*s};
    } else if (t < 23) {                        // layer-1 gate table (7)
        int tt = t - 16;
        computeU(params, 1, b_qb(tt), Ush[tt]);
    }
    __syncthreads();                             // V + Ush ready

    const int f0 = fixb & 1, f1 = (fixb >> 1) & 1, f2b = (fixb >> 2) & 1;
    const int t0 = t & 1,  t7 = (t >> 7) & 1;

    // pre = prod_{beta=4..13}
    f2 pre = V[4][(t ^ (t >> 1)) & 1];
    #pragma unroll
    for (int bb = 5; bb <= 10; ++bb)
        pre = cmulpk(pre, V[bb][((t >> (bb - 4)) ^ (t >> (bb - 3))) & 1]);
    pre = cmulpk(pre, V[11][t7 ^ f0]);
    pre = cmulpk(pre, V[12][f0 ^ f1]);
    pre = cmulpk(pre, V[13][f1 ^ f2b]);

    f2 P0 = cmulpk(pre, V[3][t0]);               // a0=0
    f2 P1 = cmulpk(pre, V[3][1 ^ t0]);           // a0=1
    f2 Q[4];                                     // Q[a0 + 2*e4] = P[a0]*V[2][e4]
    Q[0] = cmulpk(P0, V[2][0]); Q[1] = cmulpk(P1, V[2][0]);
    Q[2] = cmulpk(P0, V[2][1]); Q[3] = cmulpk(P1, V[2][1]);
    f2 Rr[4];                                    // Rr[e2 + 2*e3] = V[0][e2]*V[1][e3]
    Rr[0] = cmulpk(V[0][0], V[1][0]); Rr[1] = cmulpk(V[0][1], V[1][0]);
    Rr[2] = cmulpk(V[0][0], V[1][1]); Rr[3] = cmulpk(V[0][1], V[1][1]);
    f2 G0 = cmulpk(V[15][0], V[14][f2b]);        // e1=0
    f2 G1 = cmulpk(V[15][1], V[14][1 ^ f2b]);    // e1=1
    f2 TT[8];                                    // TT[e1 + 2*e2 + 4*e3]
    #pragma unroll
    for (int e = 0; e < 4; ++e) {
        TT[2*e]     = cmulpk(G0, Rr[e]);
        TT[2*e + 1] = cmulpk(G1, Rr[e]);
    }

    f2 A[32];
    #pragma unroll
    for (int a = 0; a < 32; ++a) {
        const int a0 = a & 1;
        const int e1 = ((a >> 1) ^ (a >> 2)) & 1;
        const int e2 = ((a >> 2) ^ (a >> 3)) & 1;
        const int e3 = ((a >> 3) ^ (a >> 4)) & 1;
        const int e4 = ((a >> 4) ^  a      ) & 1;
        A[a] = cmulpk(Q[a0 + 2*e4], TT[e1 + 2*e2 + 4*e3]);
    }

    // arr1 gates (layer 1): d10..12 -> q15,q14,q13
    gate32<4> (A, Ush[0][0], Ush[0][1], Ush[0][2], Ush[0][3]);
    gate32<8> (A, Ush[1][0], Ush[1][1], Ush[1][2], Ush[1][3]);
    gate32<16>(A, Ush[2][0], Ush[2][1], Ush[2][2], Ush[2][3]);

    transpose_1to3(A, S, t);
    gate32<1>(A, Ush[3][0], Ush[3][1], Ush[3][2], Ush[3][3]);   // d5 q7
    gate32<2>(A, Ush[4][0], Ush[4][1], Ush[4][2], Ush[4][3]);   // d6 q6
    gate32<4>(A, Ush[5][0], Ush[5][1], Ush[5][2], Ush[5][3]);   // d7 q5
    gate32<8>(A, Ush[6][0], Ush[6][1], Ush[6][2], Ush[6][3]);   // d8 q4

    // direct store from arr3 (no perm)
    #pragma unroll
    for (int h = 0; h < 2; ++h) {
        #pragma unroll
        for (int rr = 0; rr < 16; ++rr) {
            int d = (t & 31) | (rr << 5) | (((t >> 5) & 7) << 9) | (h << 12);
            int m = (d & 511) | (fixb << 9) | (((d >> 9) & 1) << 12) | ((d >> 10) << 13);
            base[m] = A[h*16 + rr];
        }
    }
}

// Sweep 3: tail(lm-1) rename + layer-lm gates on 7 B-local qubits.
__global__ __launch_bounds__(TPB, 4) void qc_B_heavy(
    const float* __restrict__ params, f2* __restrict__ st, int lm)
{
    __shared__ __align__(16) f2 S[4096];
    __shared__ f2 Ush[7][4];

    const int t    = threadIdx.x;
    const int b    = blockIdx.x >> 3;
    const int fixb = blockIdx.x & 7;            // g bits 12..14
    f2* base = st + ((size_t)b << NQ);

    if (t < 7) computeU(params, lm, b_qb(t), Ush[t]);

    // load arr1-d: reg a: bit0 = d0, bits1..4 = d9..12; thread bits = d1..8
    f2 R[32];
    #pragma unroll
    for (int k = 0; k < 16; ++k) {
        int j = 2*(t + 256*k);
        int m = (j & 511) | (fixb << 9) | (((j >> 9) & 1) << 12) | ((j >> 10) << 13);
        float4 v = *(const float4*)(base + m);
        R[2*k]   = (f2){v.x, v.y};
        R[2*k+1] = (f2){v.z, v.w};
    }
    // tail perm of layer lm-1: pure compile-time register rename
    f2 A[32];
    #pragma unroll
    for (int a = 0; a < 32; ++a) A[a] = R[permB(a)];
    __syncthreads();                             // Ush ready

    // arr1 gates (layer lm): d10..12 -> q15,q14,q13
    gate32<4> (A, Ush[0][0], Ush[0][1], Ush[0][2], Ush[0][3]);
    gate32<8> (A, Ush[1][0], Ush[1][1], Ush[1][2], Ush[1][3]);
    gate32<16>(A, Ush[2][0], Ush[2][1], Ush[2][2], Ush[2][3]);

    transpose_1to3(A, S, t);
    gate32<1>(A, Ush[3][0], Ush[3][1], Ush[3][2], Ush[3][3]);   // d5 q7
    gate32<2>(A, Ush[4][0], Ush[4][1], Ush[4][2], Ush[4][3]);   // d6 q6
    gate32<4>(A, Ush[5][0], Ush[5][1], Ush[5][2], Ush[5][3]);   // d7 q5
    gate32<8>(A, Ush[6][0], Ush[6][1], Ush[6][2], Ush[6][3]);   // d8 q4

    // direct store from arr3 (no perm)
    #pragma unroll
    for (int h = 0; h < 2; ++h) {
        #pragma unroll
        for (int rr = 0; rr < 16; ++rr) {
            int d = (t & 31) | (rr << 5) | (((t >> 5) & 7) << 9) | (h << 12);
            int m = (d & 511) | (fixb << 9) | (((d >> 9) & 1) << 12) | ((d >> 10) << 13);
            base[m] = A[h*16 + rr];
        }
    }
}

// Sweeps 2,4: layer-l gates x9 (5 natural + 4 after nat->arr2 transpose)
// + main(l) with R9's verbatim interleaved writeback.  stealL>=0 adds the
// stolen layer-stealL gates q3,q2,q1 as an in-LDS pass on the staged array
// (pair masks lab^3/6/12, roles d9/d10/d11 = i-suffix parities ^ h).
__global__ __launch_bounds__(TPB, 4) void qc_A_lite(
    const float* __restrict__ params, f2* __restrict__ st, int layer, int stealL)
{
    __shared__ __align__(16) f2 S[4096];
    __shared__ f2 Ush[9][4];
    __shared__ f2 Uq[3][4];
    const int t    = threadIdx.x;
    const int b    = blockIdx.x >> 3;
    const int fix3 = blockIdx.x & 7;
    f2* base = st + ((size_t)b << NQ) + (fix3 << 13);

    if (t < 9) computeU(params, layer, a_qb(t), Ush[t]);
    if (stealL >= 0 && t >= 16 && t < 19)        // Uq[0]=q3 Uq[1]=q2 Uq[2]=q1
        computeU(params, stealL, 3 - (t - 16), Uq[t - 16]);

    f2 A[32];
    const float4* src = (const float4*)base;
    #pragma unroll
    for (int k = 0; k < 16; ++k) {
        float4 v = src[t + 256*k];
        A[2*k]   = (f2){v.x, v.y};
        A[2*k+1] = (f2){v.z, v.w};
    }
    __syncthreads();                             // U tables ready

    // natural gates: j0 q12, j9 q3, j10 q2, j11 q1, j12 q0
    gate32<1> (A, Ush[0][0], Ush[0][1], Ush[0][2], Ush[0][3]);
    gate32<2> (A, Ush[1][0], Ush[1][1], Ush[1][2], Ush[1][3]);
    gate32<4> (A, Ush[2][0], Ush[2][1], Ush[2][2], Ush[2][3]);
    gate32<8> (A, Ush[3][0], Ush[3][1], Ush[3][2], Ush[3][3]);
    gate32<16>(A, Ush[4][0], Ush[4][1], Ush[4][2], Ush[4][3]);

    transpose_1to2(A, S, t);
    // arr2 gates: j1 q11, j2 q10, j3 q9, j4 q8
    gate32<1>(A, Ush[5][0], Ush[5][1], Ush[5][2], Ush[5][3]);
    gate32<2>(A, Ush[6][0], Ush[6][1], Ush[6][2], Ush[6][3]);
    gate32<4>(A, Ush[7][0], Ush[7][1], Ush[7][2], Ush[7][3]);
    gate32<8>(A, Ush[8][0], Ush[8][1], Ush[8][2], Ush[8][3]);

    // writeback: stage at arr2 positions; optional in-LDS stolen-gate pass;
    // then R9-verbatim interleaved perm-read -> float4 store.
    float4* dst = (float4*)base;
    #pragma unroll
    for (int h = 0; h < 2; ++h) {
        __syncthreads();
        #pragma unroll
        for (int rr = 0; rr < 16; ++rr) {        // arr2 positions
            int jj = (t & 1) | (rr << 1) | (((t >> 1) & 15) << 5) | (((t >> 5) & 7) << 9);
            S[jj ^ (((t >> 1) & 7) << 1)] = A[h*16 + rr];
        }
        __syncthreads();
        if (stealL >= 0) {
            // thread t owns labels lab=0..15 at staged indices i = t | (lab<<8)
            f2 E[16];
            #pragma unroll
            for (int lab = 0; lab < 16; ++lab) {
                int i = t | (lab << 8);
                E[lab] = S[i ^ (((i >> 5) & 7) << 1)];
            }
            // q3 (D9):  pair mask 3,  role = par(lab & 0b1110) ^ h
            gateE<3, 14>(E, h, Uq[0][0], Uq[0][1], Uq[0][2], Uq[0][3]);
            // q2 (D10): pair mask 6,  role = par(lab & 0b1100) ^ h
            gateE<6, 12>(E, h, Uq[1][0], Uq[1][1], Uq[1][2], Uq[1][3]);
            // q1 (D11): pair mask 12, role = par(lab & 0b1000) ^ h
            gateE<12, 8>(E, h, Uq[2][0], Uq[2][1], Uq[2][2], Uq[2][3]);
            #pragma unroll
            for (int lab = 0; lab < 16; ++lab) {
                int i = t | (lab << 8);
                S[i ^ (((i >> 5) & 7) << 1)] = E[lab];
            }
            __syncthreads();
        }
        #pragma unroll
        for (int k = 0; k < 8; ++k) {            // dest d' = 2(t+256k), bit12 = h
            int d  = 2*(t + 256*k);
            int i0 = d ^ (d >> 1) ^ (h << 11);
            int i1 = (d+1) ^ ((d+1) >> 1) ^ (h << 11);
            f2 a0 = S[i0 ^ (((i0 >> 5) & 7) << 1)];
            f2 a1 = S[i1 ^ (((i1 >> 5) & 7) << 1)];
            dst[(t + 256*k) | (h << 11)] = make_float4(a0.x, a0.y, a1.x, a1.y);
        }
    }
}

// Sweep 5: tail2 rename + L3 x13 + chain3-relabel expZ.  Read-only.
// arr3 amp coords: g0=t6, g1=t7, g2=h, g3..7=t0..4, g8..11=rr, g12..14=fixb,
// g15=t5.  Final f_b = parity(g>>b) (b<=14), f15 = parity(g&0x7FFF).
// Sign buckets over (rr,h): M0 uniform; M1 ±par(rr); M2 ±par(rr>>1);
// M3 ±par(rr>>2); M4 ±rr3; M5 ±(par(rr)^h).  [R10-verified algebra]
__global__ __launch_bounds__(TPB, 4) void qc_B_final(
    const float* __restrict__ params, const f2* __restrict__ st,
    float* __restrict__ out)
{
    __shared__ __align__(16) f2 S[4096];         // transpose buffer, reused as F
    __shared__ f2 Ush[13][4];
    float* F = (float*)S;                         // 16*272 = 4352 floats <= 8192

    const int t    = threadIdx.x;
    const int b    = blockIdx.x >> 3;
    const int fixb = blockIdx.x & 7;
    const f2* base = st + ((size_t)b << NQ);

    if (t < 13) computeU(params, 3, bf_qb(t), Ush[t]);

    f2 R[32];
    #pragma unroll
    for (int k = 0; k < 16; ++k) {
        int j = 2*(t + 256*k);
        int m = (j & 511) | (fixb << 9) | (((j >> 9) & 1) << 12) | ((j >> 10) << 13);
        float4 v = *(const float4*)(base + m);
        R[2*k]   = (f2){v.x, v.y};
        R[2*k+1] = (f2){v.z, v.w};
    }
    f2 A[32];
    #pragma unroll
    for (int a = 0; a < 32; ++a) A[a] = R[permB(a)];   // tail2 rename
    __syncthreads();                             // Ush ready

    // arr1 gates: d0 q12, d9 q0, d10..12 q15,q14,q13
    gate32<1> (A, Ush[0][0],  Ush[0][1],  Ush[0][2],  Ush[0][3]);
    gate32<2> (A, Ush[1][0],  Ush[1][1],  Ush[1][2],  Ush[1][3]);
    gate32<4> (A, Ush[2][0],  Ush[2][1],  Ush[2][2],  Ush[2][3]);
    gate32<8> (A, Ush[3][0],  Ush[3][1],  Ush[3][2],  Ush[3][3]);
    gate32<16>(A, Ush[4][0],  Ush[4][1],  Ush[4][2],  Ush[4][3]);

    transpose_1to2(A, S, t);
    // arr2 gates: d1..4 -> q11,q10,q9,q8
    gate32<1>(A, Ush[5][0], Ush[5][1], Ush[5][2], Ush[5][3]);
    gate32<2>(A, Ush[6][0], Ush[6][1], Ush[6][2], Ush[6][3]);
    gate32<4>(A, Ush[7][0], Ush[7][1], Ush[7][2], Ush[7][3]);
    gate32<8>(A, Ush[8][0], Ush[8][1], Ush[8][2], Ush[8][3]);

    transpose_2to3(A, S, t);
    // arr3 gates: d5..8 -> q7,q6,q5,q4
    gate32<1>(A, Ush[9][0],  Ush[9][1],  Ush[9][2],  Ush[9][3]);
    gate32<2>(A, Ush[10][0], Ush[10][1], Ush[10][2], Ush[10][3]);
    gate32<4>(A, Ush[11][0], Ush[11][1], Ush[11][2], Ush[11][3]);
    gate32<8>(A, Ush[12][0], Ush[12][1], Ush[12][2], Ush[12][3]);

    // 6 sign buckets over register slots (h, rr)
    float M0 = 0.f, M1 = 0.f, M2 = 0.f, M3 = 0.f, M4 = 0.f, M5 = 0.f;
    #pragma unroll
    for (int h = 0; h < 2; ++h) {
        #pragma unroll
        for (int rr = 0; rr < 16; ++rr) {
            f2 v = A[h*16 + rr];
            float p = v.x*v.x + v.y*v.y;
            M0 += p;
            M1 += (__popc(rr)      & 1) ? -p : p;
            M2 += (__popc(rr >> 1) & 1) ? -p : p;
            M3 += (__popc(rr >> 2) & 1) ? -p : p;
            M4 += (rr >> 3)             ? -p : p;
            M5 += ((__popc(rr) ^ h) & 1) ? -p : p;
        }
    }

    const int pf   = __popc(fixb) & 1;
    const int t5b  = (t >> 5) & 1, t6b = (t >> 6) & 1, t7b = (t >> 7) & 1;
    const int pt04 = __popc(t & 31) & 1;
    const int bs   = pf ^ t5b;                   // base sign for mid qubits

    float acc[NQ];
    acc[0]  = ((t6b ^ t7b ^ pt04 ^ pf) & 1) ? -M5 : M5;          // q0  (f15)
    acc[1]  = (((fixb >> 2) ^ t5b) & 1)      ? -M0 : M0;          // q1  (f14)
    acc[2]  = ((__popc(fixb >> 1) ^ t5b) & 1)? -M0 : M0;          // q2  (f13)
    acc[3]  = (bs & 1)                        ? -M0 : M0;          // q3  (f12)
    acc[4]  = (bs & 1)                        ? -M4 : M4;          // q4  (f11)
    acc[5]  = (bs & 1)                        ? -M3 : M3;          // q5  (f10)
    acc[6]  = (bs & 1)                        ? -M2 : M2;          // q6  (f9)
    acc[7]  = (bs & 1)                        ? -M1 : M1;          // q7  (f8)
    acc[8]  = ((((t >> 4) & 1) ^ bs) & 1)     ? -M1 : M1;          // q8  (f7)
    acc[9]  = ((__popc((t >> 3) & 3)  ^ bs) & 1) ? -M1 : M1;       // q9  (f6)
    acc[10] = ((__popc((t >> 2) & 7)  ^ bs) & 1) ? -M1 : M1;       // q10 (f5)
    acc[11] = ((__popc((t >> 1) & 15) ^ bs) & 1) ? -M1 : M1;       // q11 (f4)
    acc[12] = ((pt04 ^ bs) & 1)               ? -M1 : M1;          // q12 (f3)
    acc[13] = ((pt04 ^ bs) & 1)               ? -M5 : M5;          // q13 (f2)
    acc[14] = ((t7b ^ pt04 ^ bs) & 1)         ? -M5 : M5;          // q14 (f1)
    acc[15] = ((t6b ^ t7b ^ pt04 ^ bs) & 1)   ? -M5 : M5;          // q15 (f0)

    __syncthreads();                             // S reads done; reuse as F
    #pragma unroll
    for (int q = 0; q < NQ; ++q) F[q*272 + t] = acc[q];
    __syncthreads();
    const int qq = t >> 4, ii = t & 15;
    float s = 0.f;
    #pragma unroll
    for (int c = 0; c < 16; ++c) s += F[qq*272 + ii + 16*c];
    s += __shfl_down(s, 8, 16);
    s += __shfl_down(s, 4, 16);
    s += __shfl_down(s, 2, 16);
    s += __shfl_down(s, 1, 16);
    if (ii == 0) atomicAdd(&out[b*NQ + qq], s);
}

extern "C" void kernel_launch(void* const* d_in, const int* in_sizes, int n_in,
                              void* d_out, int out_size, void* d_ws, size_t ws_size,
                              hipStream_t stream)
{
    (void)in_sizes; (void)n_in; (void)ws_size;
    const float* x      = (const float*)d_in[0];   // (512,16) fp32
    const float* params = (const float*)d_in[1];   // (4,16,3) fp32
    float* out = (float*)d_out;                    // (512,16) fp32
    f2* st = (f2*)d_ws;                            // 256 MiB state

    hipMemsetAsync(d_out, 0, (size_t)out_size * sizeof(float), stream);
    qc_B1_gen <<<dim3(512*8), dim3(TPB), 0, stream>>>(x, params, st);
    qc_A_lite <<<dim3(512*8), dim3(TPB), 0, stream>>>(params, st, 1, -1);
    qc_B_heavy<<<dim3(512*8), dim3(TPB), 0, stream>>>(params, st, 2);
    qc_A_lite <<<dim3(512*8), dim3(TPB), 0, stream>>>(params, st, 2, 3);
    qc_B_final<<<dim3(512*8), dim3(TPB), 0, stream>>>(params, st, out);
}

// Round 12
// 509.453 us; speedup vs baseline: 1.1272x; 1.0623x over previous
//
#include <hip/hip_runtime.h>

// 16-qubit, depth-4, batch-512 statevector simulator — 5-sweep, packed-FP32.
// R11 (541 us) with the L3-steal made register-local: A_steal transposes to
// register arrangement {j8..j12}, where the pullback of L3 {q3,q2,q1} through
// main2 (i = d^(d>>1)) is 3 register pair-gates (masks 3/6/12, roles
// par(a&30)/par(a&28)/par(a&24)) — zero extra LDS traffic/barriers.
// L2's middle gates q11..q8 return to B_heavy (R8-verified 11-gate form).
//
// State: 512 x 65536 complex64 = 256 MiB in d_ws.
// Reference qubit q <-> flat-index bit beta = 15-q.
// Memory layout per batch: amp with basis index g stored at m = (g>>3) | ((g&7)<<13).
// Partition A (blocks fix g bits 0..2): local j = m bits 0..12, j_b = g_{b+3}.
// Partition B (blocks fix g bits 12..14): local d: d0..8 = g3..11, d9 = g15,
//   d10..12 = g0..2.
// Chain perm = main (A-local rows 3..14, i = d^(d>>1)) o tail (B-local rename
// permB).  Legality of early steal: main2 o pullback = L3A o main2; L3A
// commutes with tail2 (disjoint supports).
// Schedule (5 sweeps):
//   1. qc_B1_gen:    analytic gen (L0+chain0 folded, product tree) + L1 x7.
//   2. qc_A_lite(1): L1 x9 + main1 (R9-verbatim).
//   3. qc_B_heavy(2): tail1 + L2 x11 (R8-verbatim form).
//   4. qc_A_steal(2,3): L2 x5 + steal-L3 {q3,q2,q1} (register) + main2.
//   5. qc_B_final:   tail2 + L3 x13 + chain3-relabel expZ (read-only).

#define NQ 16
#define TPB 256

typedef float __attribute__((ext_vector_type(2))) f2;   // (re, im)

__device__ __forceinline__ f2 f2s(float s) { return (f2){s, s}; }

// a (*) b  (complex mul, packed: pk_mul + pk_fma)
__device__ __forceinline__ f2 cmulpk(f2 a, f2 b) {
    f2 bs = { -b.y, b.x };
    f2 r = f2s(a.x) * b;
    return __builtin_elementwise_fma(f2s(a.y), bs, r);
}

// U = RY(t2) * RX(t1) * RZ(t0), row-major [u00,u01,u10,u11]
__device__ __forceinline__ void computeU(const float* params, int layer, int q, f2* U) {
    const float* p = params + (layer*NQ + q)*3;
    float s0, c0, s1, c1, s2, c2;
    sincosf(0.5f*p[0], &s0, &c0);
    sincosf(0.5f*p[1], &s1, &c1);
    sincosf(0.5f*p[2], &s2, &c2);
    f2 m00 = { c1*c0, -c1*s0};
    f2 m01 = { s1*s0, -s1*c0};
    f2 m10 = {-s1*s0, -s1*c0};
    f2 m11 = { c1*c0,  c1*s0};
    U[0] = c2*m00 - s2*m10;
    U[1] = c2*m01 - s2*m11;
    U[2] = s2*m00 + c2*m10;
    U[3] = s2*m01 + c2*m11;
}

__device__ __forceinline__ void cpair(f2& X, f2& Y, f2 u00, f2 u01, f2 u10, f2 u11) {
    f2 x = X, y = Y;
    f2 xs = { -x.y, x.x };
    f2 ys = { -y.y, y.x };
    f2 nx = f2s(u00.x) * x;
    nx = __builtin_elementwise_fma(f2s(u00.y), xs, nx);
    nx = __builtin_elementwise_fma(f2s(u01.x), y,  nx);
    nx = __builtin_elementwise_fma(f2s(u01.y), ys, nx);
    f2 ny = f2s(u10.x) * x;
    ny = __builtin_elementwise_fma(f2s(u10.y), xs, ny);
    ny = __builtin_elementwise_fma(f2s(u11.x), y,  ny);
    ny = __builtin_elementwise_fma(f2s(u11.y), ys, ny);
    X = nx; Y = ny;
}

// 1q gate on register array A[32], pairing a <-> a|MASK (a&MASK==0 is row 0).
template<int MASK>
__device__ __forceinline__ void gate32(f2* A, f2 u00, f2 u01, f2 u10, f2 u11) {
    #pragma unroll
    for (int a = 0; a < 32; ++a)
        if (!(a & MASK)) cpair(A[a], A[a | MASK], u00, u01, u10, u11);
}

// gate with XOR-pair MASK and role par(a & RM): role-0 element is row 0.
// Requires popc(MASK & RM) odd (so partners have opposite roles).
template<int MASK, int RM>
__device__ __forceinline__ void gateR(f2* A, f2 u00, f2 u01, f2 u10, f2 u11) {
    #pragma unroll
    for (int a = 0; a < 32; ++a)
        if ((__popc(a & RM) & 1) == 0) cpair(A[a], A[a ^ MASK], u00, u01, u10, u11);
}

// tail perm on B's register coords (bits = d0, d9, d10, d11, d12)
__device__ __forceinline__ constexpr int permB(int ad) {
    return (ad & 1)
         | ((((ad >> 1) ^ (ad >> 2)) & 1) << 1)
         | ((((ad >> 2) ^ (ad >> 3)) & 1) << 2)
         | ((((ad >> 3) ^ (ad >> 4)) & 1) << 3)
         | ((((ad >> 4) ^  ad      ) & 1) << 4);
}

// Transpose arr1 {0,9,10,11,12} -> arr3 {5,6,7,8,12}
__device__ __forceinline__ void transpose_1to3(f2* A, f2* S, int t) {
    #pragma unroll
    for (int h = 0; h < 2; ++h) {
        __syncthreads();
        #pragma unroll
        for (int c = 0; c < 8; ++c) {
            int slot = ((t << 1) | (c << 9)) ^ (((t >> 4) & 7) << 1);
            f2 a0 = A[h*16 + 2*c], a1 = A[h*16 + 2*c + 1];
            *(float4*)&S[slot] = make_float4(a0.x, a0.y, a1.x, a1.y);
        }
        __syncthreads();
        #pragma unroll
        for (int rr = 0; rr < 16; ++rr) {
            int jj = (t & 31) | (rr << 5) | (((t >> 5) & 7) << 9);
            A[h*16 + rr] = S[jj ^ ((rr & 7) << 1)];
        }
    }
}

// Transpose arr1 {0,9,10,11,12} -> arr2 {1,2,3,4,12}
__device__ __forceinline__ void transpose_1to2(f2* A, f2* S, int t) {
    #pragma unroll
    for (int h = 0; h < 2; ++h) {
        __syncthreads();
        #pragma unroll
        for (int c = 0; c < 8; ++c) {
            int slot = ((t << 1) | (c << 9)) ^ (((t >> 4) & 7) << 1);
            f2 a0 = A[h*16 + 2*c], a1 = A[h*16 + 2*c + 1];
            *(float4*)&S[slot] = make_float4(a0.x, a0.y, a1.x, a1.y);
        }
        __syncthreads();
        #pragma unroll
        for (int rr = 0; rr < 16; ++rr) {
            int jj = (t & 1) | (rr << 1) | (((t >> 1) & 15) << 5) | (((t >> 5) & 7) << 9);
            A[h*16 + rr] = S[jj ^ (((t >> 1) & 7) << 1)];
        }
    }
}

// Transpose arr2 {1,2,3,4,12} -> arr3 {5,6,7,8,12}
__device__ __forceinline__ void transpose_2to3(f2* A, f2* S, int t) {
    #pragma unroll
    for (int h = 0; h < 2; ++h) {
        __syncthreads();
        #pragma unroll
        for (int rr = 0; rr < 16; ++rr) {
            int jj = (t & 1) | (rr << 1) | (((t >> 1) & 15) << 5) | (((t >> 5) & 7) << 9);
            S[jj ^ (((t >> 1) & 7) << 1)] = A[h*16 + rr];
        }
        __syncthreads();
        #pragma unroll
        for (int rr = 0; rr < 16; ++rr) {
            int jj = (t & 31) | (rr << 5) | (((t >> 5) & 7) << 9);
            A[h*16 + rr] = S[jj ^ ((rr & 7) << 1)];
        }
    }
}

// B-gen Ush (7): 0:q15(d10) 1:q14(d11) 2:q13(d12) 3:q7(d5) 4:q6(d6) 5:q5(d7) 6:q4(d8)
__device__ __forceinline__ int b_qb(int tt) { return (tt < 3) ? (15 - tt) : (10 - tt); }
// A_lite Ush (9): 0:q12(j0) 1:q3(j9) 2:q2(j10) 3:q1(j11) 4:q0(j12)
//                 5:q11(j1) 6:q10(j2) 7:q9(j3) 8:q8(j4)
__device__ __forceinline__ int a_qb(int tt) { return (tt == 0) ? 12 : (tt < 5) ? (4 - tt) : (16 - tt); }
// B_heavy/B_final Ush (13, B_heavy uses 11 of them starting layout below):
// 0:q15(d10) 1:q14(d11) 2:q13(d12) 3..6:q11..q8(d1..4) 7..10:q7..q4(d5..8)
__device__ __forceinline__ int bh_qb(int tt) { return (tt < 3) ? (15 - tt) : (14 - tt); }
// B_final (13): 0:q12(d0) 1:q0(d9) 2:q15(d10) 3:q14(d11) 4:q13(d12)
//               5..8: q11..q8 (d1..4)   9..12: q7..q4 (d5..8)
__device__ __forceinline__ int bf_qb(int tt) {
    return (tt == 0) ? 12 : (tt == 1) ? 0 : (tt < 5) ? (17 - tt) : (16 - tt);
}

// Sweep 1: fused analytic generation + L1 x7.  No amplitude loads.
__global__ __launch_bounds__(TPB, 4) void qc_B1_gen(
    const float* __restrict__ x, const float* __restrict__ params,
    f2* __restrict__ st)
{
    __shared__ __align__(16) f2 S[4096];       // 32 KB transpose buffer
    __shared__ f2 Ush[7][4];
    __shared__ f2 V[16][2];

    const int t    = threadIdx.x;
    const int b    = blockIdx.x >> 3;
    const int fixb = blockIdx.x & 7;            // g bits 12..14
    f2* base = st + ((size_t)b << NQ);

    if (t < 16) {                               // qubit t, g bit 15-t
        f2 U[4];
        computeU(params, 0, t, U);
        float s, c;
        sincosf(0.5f * x[b*NQ + t], &s, &c);
        // w = U * (cos h, -i sin h)^T
        V[15 - t][0] = (f2){U[0].x*c + U[1].y*s, U[0].y*c - U[1].x*s};
        V[15 - t][1] = (f2){U[2].x*c + U[3].y*s, U[2].y*c - U[3].x*s};
    } else if (t < 23) {                        // layer-1 gate table (7)
        int tt = t - 16;
        computeU(params, 1, b_qb(tt), Ush[tt]);
    }
    __syncthreads();                             // V + Ush ready

    const int f0 = fixb & 1, f1 = (fixb >> 1) & 1, f2b = (fixb >> 2) & 1;
    const int t0 = t & 1,  t7 = (t >> 7) & 1;

    // pre = prod_{beta=4..13}
    f2 pre = V[4][(t ^ (t >> 1)) & 1];
    #pragma unroll
    for (int bb = 5; bb <= 10; ++bb)
        pre = cmulpk(pre, V[bb][((t >> (bb - 4)) ^ (t >> (bb - 3))) & 1]);
    pre = cmulpk(pre, V[11][t7 ^ f0]);
    pre = cmulpk(pre, V[12][f0 ^ f1]);
    pre = cmulpk(pre, V[13][f1 ^ f2b]);

    f2 P0 = cmulpk(pre, V[3][t0]);               // a0=0
    f2 P1 = cmulpk(pre, V[3][1 ^ t0]);           // a0=1
    f2 Q[4];                                     // Q[a0 + 2*e4] = P[a0]*V[2][e4]
    Q[0] = cmulpk(P0, V[2][0]); Q[1] = cmulpk(P1, V[2][0]);
    Q[2] = cmulpk(P0, V[2][1]); Q[3] = cmulpk(P1, V[2][1]);
    f2 Rr[4];                                    // Rr[e2 + 2*e3] = V[0][e2]*V[1][e3]
    Rr[0] = cmulpk(V[0][0], V[1][0]); Rr[1] = cmulpk(V[0][1], V[1][0]);
    Rr[2] = cmulpk(V[0][0], V[1][1]); Rr[3] = cmulpk(V[0][1], V[1][1]);
    f2 G0 = cmulpk(V[15][0], V[14][f2b]);        // e1=0
    f2 G1 = cmulpk(V[15][1], V[14][1 ^ f2b]);    // e1=1
    f2 TT[8];                                    // TT[e1 + 2*e2 + 4*e3]
    #pragma unroll
    for (int e = 0; e < 4; ++e) {
        TT[2*e]     = cmulpk(G0, Rr[e]);
        TT[2*e + 1] = cmulpk(G1, Rr[e]);
    }

    f2 A[32];
    #pragma unroll
    for (int a = 0; a < 32; ++a) {
        const int a0 = a & 1;
        const int e1 = ((a >> 1) ^ (a >> 2)) & 1;
        const int e2 = ((a >> 2) ^ (a >> 3)) & 1;
        const int e3 = ((a >> 3) ^ (a >> 4)) & 1;
        const int e4 = ((a >> 4) ^  a      ) & 1;
        A[a] = cmulpk(Q[a0 + 2*e4], TT[e1 + 2*e2 + 4*e3]);
    }

    // arr1 gates (layer 1): d10..12 -> q15,q14,q13
    gate32<4> (A, Ush[0][0], Ush[0][1], Ush[0][2], Ush[0][3]);
    gate32<8> (A, Ush[1][0], Ush[1][1], Ush[1][2], Ush[1][3]);
    gate32<16>(A, Ush[2][0], Ush[2][1], Ush[2][2], Ush[2][3]);

    transpose_1to3(A, S, t);
    gate32<1>(A, Ush[3][0], Ush[3][1], Ush[3][2], Ush[3][3]);   // d5 q7
    gate32<2>(A, Ush[4][0], Ush[4][1], Ush[4][2], Ush[4][3]);   // d6 q6
    gate32<4>(A, Ush[5][0], Ush[5][1], Ush[5][2], Ush[5][3]);   // d7 q5
    gate32<8>(A, Ush[6][0], Ush[6][1], Ush[6][2], Ush[6][3]);   // d8 q4

    // direct store from arr3 (no perm)
    #pragma unroll
    for (int h = 0; h < 2; ++h) {
        #pragma unroll
        for (int rr = 0; rr < 16; ++rr) {
            int d = (t & 31) | (rr << 5) | (((t >> 5) & 7) << 9) | (h << 12);
            int m = (d & 511) | (fixb << 9) | (((d >> 9) & 1) << 12) | ((d >> 10) << 13);
            base[m] = A[h*16 + rr];
        }
    }
}

// Sweep 3: tail1 rename + L2 gates on 11 B-local qubits (R8-verified form).
__global__ __launch_bounds__(TPB, 4) void qc_B_heavy(
    const float* __restrict__ params, f2* __restrict__ st, int lm)
{
    __shared__ __align__(16) f2 S[4096];
    __shared__ f2 Ush[11][4];

    const int t    = threadIdx.x;
    const int b    = blockIdx.x >> 3;
    const int fixb = blockIdx.x & 7;            // g bits 12..14
    f2* base = st + ((size_t)b << NQ);

    if (t < 11) computeU(params, lm, bh_qb(t), Ush[t]);

    // load arr1-d: reg a: bit0 = d0, bits1..4 = d9..12; thread bits = d1..8
    f2 R[32];
    #pragma unroll
    for (int k = 0; k < 16; ++k) {
        int j = 2*(t + 256*k);
        int m = (j & 511) | (fixb << 9) | (((j >> 9) & 1) << 12) | ((j >> 10) << 13);
        float4 v = *(const float4*)(base + m);
        R[2*k]   = (f2){v.x, v.y};
        R[2*k+1] = (f2){v.z, v.w};
    }
    // tail perm of layer lm-1: pure compile-time register rename
    f2 A[32];
    #pragma unroll
    for (int a = 0; a < 32; ++a) A[a] = R[permB(a)];
    __syncthreads();                             // Ush ready

    // arr1 gates: d10..12 -> q15,q14,q13
    gate32<4> (A, Ush[0][0], Ush[0][1], Ush[0][2], Ush[0][3]);
    gate32<8> (A, Ush[1][0], Ush[1][1], Ush[1][2], Ush[1][3]);
    gate32<16>(A, Ush[2][0], Ush[2][1], Ush[2][2], Ush[2][3]);

    transpose_1to2(A, S, t);
    // arr2 gates: d1..4 -> q11,q10,q9,q8
    gate32<1>(A, Ush[3][0], Ush[3][1], Ush[3][2], Ush[3][3]);
    gate32<2>(A, Ush[4][0], Ush[4][1], Ush[4][2], Ush[4][3]);
    gate32<4>(A, Ush[5][0], Ush[5][1], Ush[5][2], Ush[5][3]);
    gate32<8>(A, Ush[6][0], Ush[6][1], Ush[6][2], Ush[6][3]);

    transpose_2to3(A, S, t);
    // arr3 gates: d5..8 -> q7,q6,q5,q4
    gate32<1>(A, Ush[7][0],  Ush[7][1],  Ush[7][2],  Ush[7][3]);
    gate32<2>(A, Ush[8][0],  Ush[8][1],  Ush[8][2],  Ush[8][3]);
    gate32<4>(A, Ush[9][0],  Ush[9][1],  Ush[9][2],  Ush[9][3]);
    gate32<8>(A, Ush[10][0], Ush[10][1], Ush[10][2], Ush[10][3]);

    // direct store from arr3 (no perm)
    #pragma unroll
    for (int h = 0; h < 2; ++h) {
        #pragma unroll
        for (int rr = 0; rr < 16; ++rr) {
            int d = (t & 31) | (rr << 5) | (((t >> 5) & 7) << 9) | (h << 12);
            int m = (d & 511) | (fixb << 9) | (((d >> 9) & 1) << 12) | ((d >> 10) << 13);
            base[m] = A[h*16 + rr];
        }
    }
}

// Sweep 2: layer-1 gates x9 (5 natural + 4 after nat->arr2 transpose)
// + main1 with R9-verbatim interleaved writeback.
__global__ __launch_bounds__(TPB, 4) void qc_A_lite(
    const float* __restrict__ params, f2* __restrict__ st, int layer)
{
    __shared__ __align__(16) f2 S[4096];
    __shared__ f2 Ush[9][4];
    const int t    = threadIdx.x;
    const int b    = blockIdx.x >> 3;
    const int fix3 = blockIdx.x & 7;
    f2* base = st + ((size_t)b << NQ) + (fix3 << 13);

    if (t < 9) computeU(params, layer, a_qb(t), Ush[t]);

    f2 A[32];
    const float4* src = (const float4*)base;
    #pragma unroll
    for (int k = 0; k < 16; ++k) {
        float4 v = src[t + 256*k];
        A[2*k]   = (f2){v.x, v.y};
        A[2*k+1] = (f2){v.z, v.w};
    }
    __syncthreads();                             // Ush ready

    // natural gates: j0 q12, j9 q3, j10 q2, j11 q1, j12 q0
    gate32<1> (A, Ush[0][0], Ush[0][1], Ush[0][2], Ush[0][3]);
    gate32<2> (A, Ush[1][0], Ush[1][1], Ush[1][2], Ush[1][3]);
    gate32<4> (A, Ush[2][0], Ush[2][1], Ush[2][2], Ush[2][3]);
    gate32<8> (A, Ush[3][0], Ush[3][1], Ush[3][2], Ush[3][3]);
    gate32<16>(A, Ush[4][0], Ush[4][1], Ush[4][2], Ush[4][3]);

    transpose_1to2(A, S, t);
    // arr2 gates: j1 q11, j2 q10, j3 q9, j4 q8
    gate32<1>(A, Ush[5][0], Ush[5][1], Ush[5][2], Ush[5][3]);
    gate32<2>(A, Ush[6][0], Ush[6][1], Ush[6][2], Ush[6][3]);
    gate32<4>(A, Ush[7][0], Ush[7][1], Ush[7][2], Ush[7][3]);
    gate32<8>(A, Ush[8][0], Ush[8][1], Ush[8][2], Ush[8][3]);

    // writeback: stage at arr2 positions, interleaved perm-read -> store
    float4* dst = (float4*)base;
    #pragma unroll
    for (int h = 0; h < 2; ++h) {
        __syncthreads();
        #pragma unroll
        for (int rr = 0; rr < 16; ++rr) {        // arr2 positions
            int jj = (t & 1) | (rr << 1) | (((t >> 1) & 15) << 5) | (((t >> 5) & 7) << 9);
            S[jj ^ (((t >> 1) & 7) << 1)] = A[h*16 + rr];
        }
        __syncthreads();
        #pragma unroll
        for (int k = 0; k < 8; ++k) {            // dest d' = 2(t+256k), bit12 = h
            int d  = 2*(t + 256*k);
            int i0 = d ^ (d >> 1) ^ (h << 11);
            int i1 = (d+1) ^ ((d+1) >> 1) ^ (h << 11);
            f2 a0 = S[i0 ^ (((i0 >> 5) & 7) << 1)];
            f2 a1 = S[i1 ^ (((i1 >> 5) & 7) << 1)];
            dst[(t + 256*k) | (h << 11)] = make_float4(a0.x, a0.y, a1.x, a1.y);
        }
    }
}

// Sweep 4: L2 gates {q12,q3,q2,q1,q0} (natural) + steal-L3 {q3,q2,q1}
// (register-local in arrangement {j8..j12}) + main2.
__global__ __launch_bounds__(TPB, 4) void qc_A_steal(
    const float* __restrict__ params, f2* __restrict__ st, int layer, int stealL)
{
    __shared__ __align__(16) f2 S[4096];
    __shared__ f2 Ush[5][4];
    __shared__ f2 Uq[3][4];
    const int t    = threadIdx.x;
    const int b    = blockIdx.x >> 3;
    const int fix3 = blockIdx.x & 7;
    f2* base = st + ((size_t)b << NQ) + (fix3 << 13);

    if (t < 5) computeU(params, layer, (t == 0) ? 12 : 4 - t, Ush[t]);  // q12,q3,q2,q1,q0
    if (t >= 16 && t < 19) computeU(params, stealL, 3 - (t - 16), Uq[t - 16]); // q3,q2,q1

    f2 A[32];
    const float4* src = (const float4*)base;
    #pragma unroll
    for (int k = 0; k < 16; ++k) {
        float4 v = src[t + 256*k];
        A[2*k]   = (f2){v.x, v.y};
        A[2*k+1] = (f2){v.z, v.w};
    }
    __syncthreads();                             // U tables ready

    // natural gates: j0 q12, j9 q3, j10 q2, j11 q1, j12 q0
    gate32<1> (A, Ush[0][0], Ush[0][1], Ush[0][2], Ush[0][3]);
    gate32<2> (A, Ush[1][0], Ush[1][1], Ush[1][2], Ush[1][3]);
    gate32<4> (A, Ush[2][0], Ush[2][1], Ush[2][2], Ush[2][3]);
    gate32<8> (A, Ush[3][0], Ush[3][1], Ush[3][2], Ush[3][3]);
    gate32<16>(A, Ush[4][0], Ush[4][1], Ush[4][2], Ush[4][3]);

    // Transpose natural {0,9,10,11,12} -> {8,9,10,11,12}:
    // write (existing arr1 float4 pattern), read idx = t | (rr<<8),
    // reg a: a0=j8 (rr0), a1..3=j9..11 (rr1..3), a4=j12 (h).
    #pragma unroll
    for (int h = 0; h < 2; ++h) {
        __syncthreads();
        #pragma unroll
        for (int c = 0; c < 8; ++c) {
            int slot = ((t << 1) | (c << 9)) ^ (((t >> 4) & 7) << 1);
            f2 a0 = A[h*16 + 2*c], a1 = A[h*16 + 2*c + 1];
            *(float4*)&S[slot] = make_float4(a0.x, a0.y, a1.x, a1.y);
        }
        __syncthreads();
        #pragma unroll
        for (int rr = 0; rr < 16; ++rr) {
            int idx = t | (rr << 8);
            A[h*16 + rr] = S[idx ^ (((idx >> 5) & 7) << 1)];
        }
    }

    // Steal: pullback of L3 {q3,q2,q1} through main2 (i = d^(d>>1)):
    //   q3: pairs a^3  (j8^j9),  role par(a&30)  (= d9)
    //   q2: pairs a^6  (j9^j10), role par(a&28)  (= d10)
    //   q1: pairs a^12 (j10^j11),role par(a&24)  (= d11)
    gateR<3, 30>(A, Uq[0][0], Uq[0][1], Uq[0][2], Uq[0][3]);
    gateR<6, 28>(A, Uq[1][0], Uq[1][1], Uq[1][2], Uq[1][3]);
    gateR<12,24>(A, Uq[2][0], Uq[2][1], Uq[2][2], Uq[2][3]);

    // Stage {8..12} back to j-natural S, then R9-verbatim perm-read + store.
    float4* dst = (float4*)base;
    #pragma unroll
    for (int h = 0; h < 2; ++h) {
        __syncthreads();
        #pragma unroll
        for (int rr = 0; rr < 16; ++rr) {
            int idx = t | (rr << 8);
            S[idx ^ (((idx >> 5) & 7) << 1)] = A[h*16 + rr];
        }
        __syncthreads();
        #pragma unroll
        for (int k = 0; k < 8; ++k) {            // dest d' = 2(t+256k), bit12 = h
            int d  = 2*(t + 256*k);
            int i0 = d ^ (d >> 1) ^ (h << 11);
            int i1 = (d+1) ^ ((d+1) >> 1) ^ (h << 11);
            f2 a0 = S[i0 ^ (((i0 >> 5) & 7) << 1)];
            f2 a1 = S[i1 ^ (((i1 >> 5) & 7) << 1)];
            dst[(t + 256*k) | (h << 11)] = make_float4(a0.x, a0.y, a1.x, a1.y);
        }
    }
}

// Sweep 5: tail2 rename + L3 x13 + chain3-relabel expZ.  Read-only.
// arr3 amp coords: g0=t6, g1=t7, g2=h, g3..7=t0..4, g8..11=rr, g12..14=fixb,
// g15=t5.  Sign buckets [R10/R11-verified algebra].
__global__ __launch_bounds__(TPB, 4) void qc_B_final(
    const float* __restrict__ params, const f2* __restrict__ st,
    float* __restrict__ out)
{
    __shared__ __align__(16) f2 S[4096];         // transpose buffer, reused as F
    __shared__ f2 Ush[13][4];
    float* F = (float*)S;                         // 16*272 = 4352 floats <= 8192

    const int t    = threadIdx.x;
    const int b    = blockIdx.x >> 3;
    const int fixb = blockIdx.x & 7;
    const f2* base = st + ((size_t)b << NQ);

    if (t < 13) computeU(params, 3, bf_qb(t), Ush[t]);

    f2 R[32];
    #pragma unroll
    for (int k = 0; k < 16; ++k) {
        int j = 2*(t + 256*k);
        int m = (j & 511) | (fixb << 9) | (((j >> 9) & 1) << 12) | ((j >> 10) << 13);
        float4 v = *(const float4*)(base + m);
        R[2*k]   = (f2){v.x, v.y};
        R[2*k+1] = (f2){v.z, v.w};
    }
    f2 A[32];
    #pragma unroll
    for (int a = 0; a < 32; ++a) A[a] = R[permB(a)];   // tail2 rename
    __syncthreads();                             // Ush ready

    // arr1 gates: d0 q12, d9 q0, d10..12 q15,q14,q13
    gate32<1> (A, Ush[0][0],  Ush[0][1],  Ush[0][2],  Ush[0][3]);
    gate32<2> (A, Ush[1][0],  Ush[1][1],  Ush[1][2],  Ush[1][3]);
    gate32<4> (A, Ush[2][0],  Ush[2][1],  Ush[2][2],  Ush[2][3]);
    gate32<8> (A, Ush[3][0],  Ush[3][1],  Ush[3][2],  Ush[3][3]);
    gate32<16>(A, Ush[4][0],  Ush[4][1],  Ush[4][2],  Ush[4][3]);

    transpose_1to2(A, S, t);
    // arr2 gates: d1..4 -> q11,q10,q9,q8
    gate32<1>(A, Ush[5][0], Ush[5][1], Ush[5][2], Ush[5][3]);
    gate32<2>(A, Ush[6][0], Ush[6][1], Ush[6][2], Ush[6][3]);
    gate32<4>(A, Ush[7][0], Ush[7][1], Ush[7][2], Ush[7][3]);
    gate32<8>(A, Ush[8][0], Ush[8][1], Ush[8][2], Ush[8][3]);

    transpose_2to3(A, S, t);
    // arr3 gates: d5..8 -> q7,q6,q5,q4
    gate32<1>(A, Ush[9][0],  Ush[9][1],  Ush[9][2],  Ush[9][3]);
    gate32<2>(A, Ush[10][0], Ush[10][1], Ush[10][2], Ush[10][3]);
    gate32<4>(A, Ush[11][0], Ush[11][1], Ush[11][2], Ush[11][3]);
    gate32<8>(A, Ush[12][0], Ush[12][1], Ush[12][2], Ush[12][3]);

    // 6 sign buckets over register slots (h, rr)
    float M0 = 0.f, M1 = 0.f, M2 = 0.f, M3 = 0.f, M4 = 0.f, M5 = 0.f;
    #pragma unroll
    for (int h = 0; h < 2; ++h) {
        #pragma unroll
        for (int rr = 0; rr < 16; ++rr) {
            f2 v = A[h*16 + rr];
            float p = v.x*v.x + v.y*v.y;
            M0 += p;
            M1 += (__popc(rr)      & 1) ? -p : p;
            M2 += (__popc(rr >> 1) & 1) ? -p : p;
            M3 += (__popc(rr >> 2) & 1) ? -p : p;
            M4 += (rr >> 3)             ? -p : p;
            M5 += ((__popc(rr) ^ h) & 1) ? -p : p;
        }
    }

    const int pf   = __popc(fixb) & 1;
    const int t5b  = (t >> 5) & 1, t6b = (t >> 6) & 1, t7b = (t >> 7) & 1;
    const int pt04 = __popc(t & 31) & 1;
    const int bs   = pf ^ t5b;                   // base sign for mid qubits

    float acc[NQ];
    acc[0]  = ((t6b ^ t7b ^ pt04 ^ pf) & 1) ? -M5 : M5;          // q0  (f15)
    acc[1]  = (((fixb >> 2) ^ t5b) & 1)      ? -M0 : M0;          // q1  (f14)
    acc[2]  = ((__popc(fixb >> 1) ^ t5b) & 1)? -M0 : M0;          // q2  (f13)
    acc[3]  = (bs & 1)                        ? -M0 : M0;          // q3  (f12)
    acc[4]  = (bs & 1)                        ? -M4 : M4;          // q4  (f11)
    acc[5]  = (bs & 1)                        ? -M3 : M3;          // q5  (f10)
    acc[6]  = (bs & 1)                        ? -M2 : M2;          // q6  (f9)
    acc[7]  = (bs & 1)                        ? -M1 : M1;          // q7  (f8)
    acc[8]  = ((((t >> 4) & 1) ^ bs) & 1)     ? -M1 : M1;          // q8  (f7)
    acc[9]  = ((__popc((t >> 3) & 3)  ^ bs) & 1) ? -M1 : M1;       // q9  (f6)
    acc[10] = ((__popc((t >> 2) & 7)  ^ bs) & 1) ? -M1 : M1;       // q10 (f5)
    acc[11] = ((__popc((t >> 1) & 15) ^ bs) & 1) ? -M1 : M1;       // q11 (f4)
    acc[12] = ((pt04 ^ bs) & 1)               ? -M1 : M1;          // q12 (f3)
    acc[13] = ((pt04 ^ bs) & 1)               ? -M5 : M5;          // q13 (f2)
    acc[14] = ((t7b ^ pt04 ^ bs) & 1)         ? -M5 : M5;          // q14 (f1)
    acc[15] = ((t6b ^ t7b ^ pt04 ^ bs) & 1)   ? -M5 : M5;          // q15 (f0)

    __syncthreads();                             // S reads done; reuse as F
    #pragma unroll
    for (int q = 0; q < NQ; ++q) F[q*272 + t] = acc[q];
    __syncthreads();
    const int qq = t >> 4, ii = t & 15;
    float s = 0.f;
    #pragma unroll
    for (int c = 0; c < 16; ++c) s += F[qq*272 + ii + 16*c];
    s += __shfl_down(s, 8, 16);
    s += __shfl_down(s, 4, 16);
    s += __shfl_down(s, 2, 16);
    s += __shfl_down(s, 1, 16);
    if (ii == 0) atomicAdd(&out[b*NQ + qq], s);
}

extern "C" void kernel_launch(void* const* d_in, const int* in_sizes, int n_in,
                              void* d_out, int out_size, void* d_ws, size_t ws_size,
                              hipStream_t stream)
{
    (void)in_sizes; (void)n_in; (void)ws_size;
    const float* x      = (const float*)d_in[0];   // (512,16) fp32
    const float* params = (const float*)d_in[1];   // (4,16,3) fp32
    float* out = (float*)d_out;                    // (512,16) fp32
    f2* st = (f2*)d_ws;                            // 256 MiB state

    hipMemsetAsync(d_out, 0, (size_t)out_size * sizeof(float), stream);
    qc_B1_gen <<<dim3(512*8), dim3(TPB), 0, stream>>>(x, params, st);
    qc_A_lite <<<dim3(512*8), dim3(TPB), 0, stream>>>(params, st, 1);
    qc_B_heavy<<<dim3(512*8), dim3(TPB), 0, stream>>>(params, st, 2);
    qc_A_steal<<<dim3(512*8), dim3(TPB), 0, stream>>>(params, st, 2, 3);
    qc_B_final<<<dim3(512*8), dim3(TPB), 0, stream>>>(params, st, out);
}